// Round 1
// baseline (239.202 us; speedup 1.0000x reference)
//
#include <hip/hip_runtime.h>
#include <hip/hip_bf16.h>

#define NB 8
#define NS 1024
#define ND 768
#define NH 12
#define NC 64
#define NEG 0.2f

typedef __attribute__((ext_vector_type(8))) short bf16x8;
typedef __attribute__((ext_vector_type(4))) float f32x4;

static __device__ __forceinline__ float bf2f(unsigned short u) {
    union { float f; unsigned int i; } v; v.i = ((unsigned int)u) << 16; return v.f;
}
static __device__ __forceinline__ unsigned short f2bf(float f) {
    union { float f; unsigned int i; } v; v.f = f;
    unsigned int r = v.i + 0x7FFFu + ((v.i >> 16) & 1u);
    return (unsigned short)(r >> 16);
}

// ---------------- fp32 -> bf16 elementwise convert ----------------
__global__ void k_f32_to_bf16(const float* __restrict__ src, unsigned short* __restrict__ dst, int n) {
    int i = (blockIdx.x * blockDim.x + threadIdx.x) * 4;
    if (i >= n) return;
    float4 v = *reinterpret_cast<const float4*>(src + i);
    ushort4 o;
    o.x = f2bf(v.x); o.y = f2bf(v.y); o.z = f2bf(v.z); o.w = f2bf(v.w);
    *reinterpret_cast<ushort4*>(dst + i) = o;
}

// ---------------- fp32 [K,N] -> bf16 [N,K] transpose-convert ----------------
__global__ void k_transpose_conv(const float* __restrict__ src, unsigned short* __restrict__ dst,
                                 int K, int N) {
    __shared__ float tile[32][33];
    int k0 = blockIdx.y * 32, n0 = blockIdx.x * 32;
    int t = threadIdx.x;           // 256 threads
    int r = t >> 3, c4 = (t & 7) * 4;
    float4 v = *reinterpret_cast<const float4*>(src + (size_t)(k0 + r) * N + n0 + c4);
    tile[r][c4] = v.x; tile[r][c4 + 1] = v.y; tile[r][c4 + 2] = v.z; tile[r][c4 + 3] = v.w;
    __syncthreads();
    ushort4 o;
    o.x = f2bf(tile[c4][r]); o.y = f2bf(tile[c4 + 1][r]);
    o.z = f2bf(tile[c4 + 2][r]); o.w = f2bf(tile[c4 + 3][r]);
    *reinterpret_cast<ushort4*>(dst + (size_t)(n0 + r) * K + k0 + c4) = o;
}

// ---------------- a_src / a_dst: [B,H,S] dot of x with att vectors ----------------
__global__ void k_attn_vec(const unsigned short* __restrict__ x, const float* __restrict__ att_src,
                           const float* __restrict__ att_dst, float* __restrict__ a_src,
                           float* __restrict__ a_dst) {
    int bs = blockIdx.x;           // 0..B*S-1
    int c = threadIdx.x;           // 0..63
    int b = bs >> 10, s = bs & 1023;
    const unsigned short* xr = x + (size_t)bs * ND;
    float ps[NH], pd[NH];
#pragma unroll
    for (int h = 0; h < NH; h++) {
        float xv = bf2f(xr[h * 64 + c]);
        ps[h] = xv * att_src[h * 64 + c];
        pd[h] = xv * att_dst[h * 64 + c];
    }
#pragma unroll
    for (int off = 32; off >= 1; off >>= 1) {
#pragma unroll
        for (int h = 0; h < NH; h++) {
            ps[h] += __shfl_down(ps[h], off, 64);
            pd[h] += __shfl_down(pd[h], off, 64);
        }
    }
    if (c == 0) {
#pragma unroll
        for (int h = 0; h < NH; h++) {
            a_src[((size_t)b * NH + h) * NS + s] = ps[h];
            a_dst[((size_t)b * NH + h) * NS + s] = pd[h];
        }
    }
}

// ---------------- per-(b,h) max over s of a_src ----------------
__global__ void k_smax(const float* __restrict__ a_src, float* __restrict__ smax) {
    int bh = blockIdx.x;
    int t = threadIdx.x;           // 256
    const float* p = a_src + (size_t)bh * NS;
    float m = -1e30f;
    for (int i = t; i < NS; i += 256) m = fmaxf(m, p[i]);
#pragma unroll
    for (int off = 32; off >= 1; off >>= 1) m = fmaxf(m, __shfl_down(m, off, 64));
    __shared__ float red[4];
    if ((t & 63) == 0) red[t >> 6] = m;
    __syncthreads();
    if (t == 0) smax[bh] = fmaxf(fmaxf(red[0], red[1]), fmaxf(red[2], red[3]));
}

// ---------------- x [B,S,H*64] bf16 -> xT [B,H,64,S] bf16 ----------------
__global__ void k_xT(const unsigned short* __restrict__ x, unsigned short* __restrict__ xT) {
    __shared__ unsigned short tile[64][72];
    int s0 = blockIdx.x * 64;
    int bh = blockIdx.y;
    int b = bh / NH, h = bh % NH;
    int t = threadIdx.x;           // 256
#pragma unroll
    for (int u = 0; u < 2; u++) {
        int idx = t + u * 256;
        int r = idx >> 3, sg = (idx & 7) * 8;
        bf16x8 v = *reinterpret_cast<const bf16x8*>(x + ((size_t)(b * NS + s0 + r)) * ND + h * 64 + sg);
        *reinterpret_cast<bf16x8*>(&tile[r][sg]) = v;
    }
    __syncthreads();
#pragma unroll
    for (int u = 0; u < 2; u++) {
        int idx = t + u * 256;
        int c = idx >> 3, sg = (idx & 7) * 8;
        unsigned short o[8];
#pragma unroll
        for (int j = 0; j < 8; j++) o[j] = tile[sg + j][c];
        *reinterpret_cast<bf16x8*>(xT + ((size_t)bh * 64 + c) * NS + s0 + sg) =
            *reinterpret_cast<const bf16x8*>(o);
    }
}

// ---------------- GEMM: C[M,N] = A[M,K] @ Bt[N,K]^T (+bias) (+acc) ----------------
// A, Bt bf16 row-major; out f32 or bf16. 128x128 tile, BK=32, 4 waves (2x2).
template <bool OUT_BF16, bool ACC, bool BIAS>
__global__ __launch_bounds__(256) void k_gemm(const unsigned short* __restrict__ A,
                                              const unsigned short* __restrict__ Bt,
                                              const float* __restrict__ bias,
                                              void* __restrict__ Cout,
                                              int M, int N, int K, int lda, int ldb) {
    __shared__ alignas(16) unsigned short sA[128][40];
    __shared__ alignas(16) unsigned short sB[128][40];
    int m0 = blockIdx.y * 128, n0 = blockIdx.x * 128;
    int t = threadIdx.x;
    int wave = t >> 6, lane = t & 63;
    int wm = wave >> 1, wn = wave & 1;
    int lr = lane & 15, kg = (lane >> 4) * 8;
    f32x4 acc[4][4] = {};
    for (int k0 = 0; k0 < K; k0 += 32) {
        __syncthreads();
#pragma unroll
        for (int u = 0; u < 2; u++) {
            int idx = t + u * 256;
            int r = idx >> 2, sg = (idx & 3) * 8;
            *reinterpret_cast<bf16x8*>(&sA[r][sg]) =
                *reinterpret_cast<const bf16x8*>(A + (size_t)(m0 + r) * lda + k0 + sg);
            *reinterpret_cast<bf16x8*>(&sB[r][sg]) =
                *reinterpret_cast<const bf16x8*>(Bt + (size_t)(n0 + r) * ldb + k0 + sg);
        }
        __syncthreads();
        bf16x8 af[4], bfr[4];
#pragma unroll
        for (int m = 0; m < 4; m++) af[m] = *reinterpret_cast<bf16x8*>(&sA[wm * 64 + m * 16 + lr][kg]);
#pragma unroll
        for (int n = 0; n < 4; n++) bfr[n] = *reinterpret_cast<bf16x8*>(&sB[wn * 64 + n * 16 + lr][kg]);
#pragma unroll
        for (int m = 0; m < 4; m++)
#pragma unroll
            for (int n = 0; n < 4; n++)
                acc[m][n] = __builtin_amdgcn_mfma_f32_16x16x32_bf16(af[m], bfr[n], acc[m][n], 0, 0, 0);
    }
    int rg = (lane >> 4) * 4;
#pragma unroll
    for (int m = 0; m < 4; m++) {
#pragma unroll
        for (int n = 0; n < 4; n++) {
            int col = n0 + wn * 64 + n * 16 + lr;
            float bv = BIAS ? bias[col] : 0.0f;
#pragma unroll
            for (int r = 0; r < 4; r++) {
                int row = m0 + wm * 64 + m * 16 + rg + r;
                float v = acc[m][n][r] + bv;
                if (OUT_BF16) {
                    ((unsigned short*)Cout)[(size_t)row * N + col] = f2bf(v);
                } else {
                    float* o = (float*)Cout + (size_t)row * N + col;
                    if (ACC) v += *o;
                    *o = v;
                }
            }
        }
    }
}

// ---------------- PV: per (b,h) softmax-weighted aggregation ----------------
// out[i,c] = (1/Z_i) * sum_j exp(lrelu(d_i+s_j)-m_i) * x[j,c];  m_i = lrelu(d_i+smax)
// block = 128 threads (2 waves), tile: 128 rows i x 64 cols c, BK=32 over j.
__global__ __launch_bounds__(128) void k_pv(const unsigned short* __restrict__ xT,
                                            const float* __restrict__ a_src,
                                            const float* __restrict__ a_dst,
                                            const float* __restrict__ smax,
                                            const float* __restrict__ b_gat,
                                            unsigned short* __restrict__ gat) {
    __shared__ alignas(16) unsigned short sW[128][40];
    __shared__ alignas(16) unsigned short sX[64][40];
    __shared__ float sS[32];
    __shared__ float sZ[128];
    int i0 = blockIdx.x * 128;
    int bh = blockIdx.y;
    int b = bh / NH, h = bh % NH;
    int t = threadIdx.x, wave = t >> 6, lane = t & 63;
    const unsigned short* xbase = xT + (size_t)bh * 64 * NS;
    const float* asrc = a_src + (size_t)bh * NS;
    float d = a_dst[(size_t)bh * NS + i0 + t];
    float sm = smax[bh];
    float dm = d + sm;
    float mi = dm > 0.f ? dm : NEG * dm;
    float Z = 0.f;
    int lr = lane & 15, kg = (lane >> 4) * 8;
    f32x4 acc[4][4] = {};
    for (int j0 = 0; j0 < NS; j0 += 32) {
        __syncthreads();
        if (t < 32) sS[t] = asrc[j0 + t];
#pragma unroll
        for (int u = 0; u < 2; u++) {
            int idx = t + u * 128;
            int c = idx >> 2, sg = (idx & 3) * 8;
            *reinterpret_cast<bf16x8*>(&sX[c][sg]) =
                *reinterpret_cast<const bf16x8*>(xbase + (size_t)c * NS + j0 + sg);
        }
        __syncthreads();
        float zloc = 0.f;
        unsigned short wloc[32];
#pragma unroll
        for (int jj = 0; jj < 32; jj++) {
            float sc = d + sS[jj];
            sc = sc > 0.f ? sc : NEG * sc;
            float w = __expf(sc - mi);
            unsigned short wb = f2bf(w);
            wloc[jj] = wb;
            zloc += bf2f(wb);
        }
        Z += zloc;
#pragma unroll
        for (int q = 0; q < 4; q++)
            *reinterpret_cast<bf16x8*>(&sW[t][q * 8]) = *reinterpret_cast<const bf16x8*>(&wloc[q * 8]);
        __syncthreads();
        bf16x8 af[4], bfr[4];
#pragma unroll
        for (int m = 0; m < 4; m++) af[m] = *reinterpret_cast<bf16x8*>(&sW[wave * 64 + m * 16 + lr][kg]);
#pragma unroll
        for (int n = 0; n < 4; n++) bfr[n] = *reinterpret_cast<bf16x8*>(&sX[n * 16 + lr][kg]);
#pragma unroll
        for (int m = 0; m < 4; m++)
#pragma unroll
            for (int n = 0; n < 4; n++)
                acc[m][n] = __builtin_amdgcn_mfma_f32_16x16x32_bf16(af[m], bfr[n], acc[m][n], 0, 0, 0);
    }
    sZ[t] = Z;
    __syncthreads();
    int rg = (lane >> 4) * 4;
#pragma unroll
    for (int m = 0; m < 4; m++) {
#pragma unroll
        for (int r = 0; r < 4; r++) {
            int rl = wave * 64 + m * 16 + rg + r;
            float rz = 1.0f / sZ[rl];
            int row = i0 + rl;
#pragma unroll
            for (int n = 0; n < 4; n++) {
                int col = n * 16 + lr;
                float v = acc[m][n][r] * rz + b_gat[h * 64 + col];
                gat[((size_t)(b * NS + row)) * ND + h * 64 + col] = f2bf(v);
            }
        }
    }
}

extern "C" void kernel_launch(void* const* d_in, const int* in_sizes, int n_in,
                              void* d_out, int out_size, void* d_ws, size_t ws_size,
                              hipStream_t stream) {
    const float* hs  = (const float*)d_in[0];
    const float* to  = (const float*)d_in[1];
    const float* Wg  = (const float*)d_in[2];
    const float* asv = (const float*)d_in[3];
    const float* adv = (const float*)d_in[4];
    const float* bg  = (const float*)d_in[5];
    const float* Wp  = (const float*)d_in[6];
    const float* bp  = (const float*)d_in[7];
    const float* Wf  = (const float*)d_in[8];
    const float* bfu = (const float*)d_in[9];
    float* out = (float*)d_out;

    char* ws = (char*)d_ws;
    size_t off = 0;
    auto alloc = [&](size_t bytes) -> void* {
        void* p = ws + off;
        off = (off + bytes + 255) & ~(size_t)255;
        return p;
    };
    const size_t NBSD = (size_t)NB * NS * ND;
    unsigned short* h_bf  = (unsigned short*)alloc(NBSD * 2);  // later reused as gat_bf
    unsigned short* x_bf  = (unsigned short*)alloc(NBSD * 2);  // later reused as graph_bf
    unsigned short* t_bf  = (unsigned short*)alloc(NBSD * 2);
    unsigned short* xT_bf = (unsigned short*)alloc(NBSD * 2);
    unsigned short* WgT   = (unsigned short*)alloc((size_t)ND * ND * 2);
    unsigned short* WpT   = (unsigned short*)alloc((size_t)ND * ND * 2);
    unsigned short* WfT   = (unsigned short*)alloc((size_t)2 * ND * ND * 2);
    float* a_src = (float*)alloc((size_t)NB * NH * NS * 4);
    float* a_dst = (float*)alloc((size_t)NB * NH * NS * 4);
    float* smax  = (float*)alloc((size_t)NB * NH * 4);

    int n = (int)NBSD;
    k_f32_to_bf16<<<n / 4 / 256, 256, 0, stream>>>(hs, h_bf, n);
    k_f32_to_bf16<<<n / 4 / 256, 256, 0, stream>>>(to, t_bf, n);
    k_transpose_conv<<<dim3(ND / 32, ND / 32), 256, 0, stream>>>(Wg, WgT, ND, ND);
    k_transpose_conv<<<dim3(ND / 32, ND / 32), 256, 0, stream>>>(Wp, WpT, ND, ND);
    k_transpose_conv<<<dim3(ND / 32, 2 * ND / 32), 256, 0, stream>>>(Wf, WfT, 2 * ND, ND);

    // GEMM1: x = hs @ W_gat  -> bf16
    k_gemm<true, false, false><<<dim3(ND / 128, NB * NS / 128), 256, 0, stream>>>(
        h_bf, WgT, nullptr, x_bf, NB * NS, ND, ND, ND, ND);

    k_attn_vec<<<NB * NS, 64, 0, stream>>>(x_bf, asv, adv, a_src, a_dst);
    k_smax<<<NB * NH, 256, 0, stream>>>(a_src, smax);
    k_xT<<<dim3(NS / 64, NB * NH), 256, 0, stream>>>(x_bf, xT_bf);

    // PV -> gat_bf (reuse h_bf region), adds b_gat
    unsigned short* gat_bf = h_bf;
    k_pv<<<dim3(NS / 128, NB * NH), 128, 0, stream>>>(xT_bf, a_src, a_dst, smax, bg, gat_bf);

    // proj: graph = gat @ W_proj + b_proj -> bf16 (reuse x_bf region)
    unsigned short* graph_bf = x_bf;
    k_gemm<true, false, true><<<dim3(ND / 128, NB * NS / 128), 256, 0, stream>>>(
        gat_bf, WpT, bp, graph_bf, NB * NS, ND, ND, ND, ND);

    // fused: out = t @ Wf[0:768,:] + graph @ Wf[768:1536,:] + b_fus   (fp32 out)
    k_gemm<false, false, true><<<dim3(ND / 128, NB * NS / 128), 256, 0, stream>>>(
        t_bf, WfT, bfu, out, NB * NS, ND, ND, ND, 2 * ND);
    k_gemm<false, true, false><<<dim3(ND / 128, NB * NS / 128), 256, 0, stream>>>(
        graph_bf, WfT + ND, nullptr, out, NB * NS, ND, ND, ND, 2 * ND);
}